// Round 1
// baseline (4257.958 us; speedup 1.0000x reference)
//
#include <hip/hip_runtime.h>
#include <hip/hip_bf16.h>
#include <math.h>

// Problem constants
constexpr int NB = 16384;   // batch rows
constexpr int NF = 2048;    // features (K)
constexpr int NI = 4096;    // intermediate (cols of h)
constexpr int NC = 1000;    // classes

// GEMM tiling
constexpr int BM = 64;
constexpr int BN = 64;
constexpr int BK = 32;
constexpr int TM = 4;
constexpr int TN = 4;
constexpr int NSPLIT = 8;                       // column splits for occupancy
constexpr int COLS_PER_SPLIT = NI / NSPLIT;     // 512
constexpr int NCHUNK = COLS_PER_SPLIT / BN;     // 8
constexpr int LDS_STRIDE = BM + 4;              // 68 floats: keeps 16B alignment, breaks bank stride

// ---------------------------------------------------------------------------
// Kernel 1: fp32 GEMM h = x @ w1^T + b1, tracking per-row running (max, idx)
// over this block's column range. Writes per-(row, split) partial argmax.
// ---------------------------------------------------------------------------
__global__ __launch_bounds__(256) void argmax_gemm(
    const float* __restrict__ x, const float* __restrict__ w1,
    const float* __restrict__ b1, float* __restrict__ pval,
    int* __restrict__ pidx) {
  __shared__ float xs[BK][LDS_STRIDE];
  __shared__ float ws[BK][LDS_STRIDE];

  const int t = threadIdx.x;
  const int tx = t & 15;   // col group
  const int ty = t >> 4;   // row group
  const int m0 = blockIdx.x * BM;
  const int split = blockIdx.y;
  const int n0 = split * COLS_PER_SPLIT;

  // staging indices: 256 threads load 64 rows x 32 k as float4, 2 passes
  const int lrow = t >> 3;        // 0..31
  const int lk4 = (t & 7) << 2;   // 0,4,...,28

  float rmax[TM];
  int ridx[TM];
#pragma unroll
  for (int i = 0; i < TM; ++i) { rmax[i] = -INFINITY; ridx[i] = 0; }

  for (int chunk = 0; chunk < NCHUNK; ++chunk) {
    const int nb = n0 + chunk * BN;
    float acc[TM][TN];
#pragma unroll
    for (int i = 0; i < TM; ++i)
#pragma unroll
      for (int j = 0; j < TN; ++j) acc[i][j] = 0.0f;

    for (int kt = 0; kt < NF; kt += BK) {
      __syncthreads();  // protect previous tile's reads
#pragma unroll
      for (int p = 0; p < 2; ++p) {
        const int row = p * 32 + lrow;
        const float4 v = *(const float4*)(x + (size_t)(m0 + row) * NF + kt + lk4);
        xs[lk4 + 0][row] = v.x;
        xs[lk4 + 1][row] = v.y;
        xs[lk4 + 2][row] = v.z;
        xs[lk4 + 3][row] = v.w;
        const float4 u = *(const float4*)(w1 + (size_t)(nb + row) * NF + kt + lk4);
        ws[lk4 + 0][row] = u.x;
        ws[lk4 + 1][row] = u.y;
        ws[lk4 + 2][row] = u.z;
        ws[lk4 + 3][row] = u.w;
      }
      __syncthreads();
#pragma unroll
      for (int k = 0; k < BK; ++k) {
        const float4 av = *(const float4*)&xs[k][ty * TM];
        const float4 bv = *(const float4*)&ws[k][tx * TN];
        const float a[TM] = {av.x, av.y, av.z, av.w};
        const float b[TN] = {bv.x, bv.y, bv.z, bv.w};
#pragma unroll
        for (int i = 0; i < TM; ++i)
#pragma unroll
          for (int j = 0; j < TN; ++j) acc[i][j] = fmaf(a[i], b[j], acc[i][j]);
      }
    }

    // fold bias, update running argmax (strict > keeps earliest col in-thread)
#pragma unroll
    for (int j = 0; j < TN; ++j) {
      const int col = nb + tx * TN + j;
      const float bj = b1[col];
#pragma unroll
      for (int i = 0; i < TM; ++i) {
        const float v = acc[i][j] + bj;
        if (v > rmax[i]) { rmax[i] = v; ridx[i] = col; }
      }
    }
  }

  // reduce across the 16 tx lanes of each ty group (ties -> smaller index)
#pragma unroll
  for (int m = 1; m < 16; m <<= 1) {
#pragma unroll
    for (int i = 0; i < TM; ++i) {
      const float v2 = __shfl_xor(rmax[i], m);
      const int i2 = __shfl_xor(ridx[i], m);
      if (v2 > rmax[i] || (v2 == rmax[i] && i2 < ridx[i])) {
        rmax[i] = v2;
        ridx[i] = i2;
      }
    }
  }
  if (tx == 0) {
#pragma unroll
    for (int i = 0; i < TM; ++i) {
      const int row = m0 + ty * TM + i;
      pval[(size_t)row * NSPLIT + split] = rmax[i];
      pidx[(size_t)row * NSPLIT + split] = ridx[i];
    }
  }
}

// ---------------------------------------------------------------------------
// Kernel 2: transpose w2 [NC x NI] -> w2t [NI x NC] for coalesced gather
// ---------------------------------------------------------------------------
__global__ __launch_bounds__(256) void transpose_w2(const float* __restrict__ w2,
                                                    float* __restrict__ w2t) {
  __shared__ float tile[32][33];
  const int x = blockIdx.x * 32 + threadIdx.x;  // col in w2 (0..NI)
  const int y0 = blockIdx.y * 32;               // row in w2 (0..NC)
  for (int j = threadIdx.y; j < 32; j += 8) {
    const int y = y0 + j;
    tile[j][threadIdx.x] = (y < NC) ? w2[(size_t)y * NI + x] : 0.0f;
  }
  __syncthreads();
  const int xo = y0 + threadIdx.x;  // col in w2t (0..NC)
  const int yo0 = blockIdx.x * 32;  // row in w2t
  for (int j = threadIdx.y; j < 32; j += 8) {
    const int yo = yo0 + j;
    if (xo < NC) w2t[(size_t)yo * NC + xo] = tile[threadIdx.x][j];
  }
}

// ---------------------------------------------------------------------------
// Kernel 3: merge per-split argmax, gather w2t row + b2 -> out (coalesced)
// ---------------------------------------------------------------------------
__global__ __launch_bounds__(256) void merge_gather(
    const float* __restrict__ pval, const int* __restrict__ pidx,
    const float* __restrict__ w2t, const float* __restrict__ b2,
    float* __restrict__ out) {
  const int b = blockIdx.x;
  __shared__ int sidx;
  if (threadIdx.x == 0) {
    float best = -INFINITY;
    int bi = 0;
    for (int s = 0; s < NSPLIT; ++s) {
      const float v = pval[(size_t)b * NSPLIT + s];
      const int ix = pidx[(size_t)b * NSPLIT + s];
      if (v > best || (v == best && ix < bi)) { best = v; bi = ix; }
    }
    sidx = bi;
  }
  __syncthreads();
  const float* src = w2t + (size_t)sidx * NC;
  for (int c = threadIdx.x; c < NC; c += 256) {
    out[(size_t)b * NC + c] = src[c] + b2[c];
  }
}

// Fallback if workspace can't hold w2t: gather straight from w2 (strided)
__global__ __launch_bounds__(256) void merge_gather_direct(
    const float* __restrict__ pval, const int* __restrict__ pidx,
    const float* __restrict__ w2, const float* __restrict__ b2,
    float* __restrict__ out) {
  const int b = blockIdx.x;
  __shared__ int sidx;
  if (threadIdx.x == 0) {
    float best = -INFINITY;
    int bi = 0;
    for (int s = 0; s < NSPLIT; ++s) {
      const float v = pval[(size_t)b * NSPLIT + s];
      const int ix = pidx[(size_t)b * NSPLIT + s];
      if (v > best || (v == best && ix < bi)) { best = v; bi = ix; }
    }
    sidx = bi;
  }
  __syncthreads();
  const int ix = sidx;
  for (int c = threadIdx.x; c < NC; c += 256) {
    out[(size_t)b * NC + c] = w2[(size_t)c * NI + ix] + b2[c];
  }
}

extern "C" void kernel_launch(void* const* d_in, const int* in_sizes, int n_in,
                              void* d_out, int out_size, void* d_ws, size_t ws_size,
                              hipStream_t stream) {
  const float* x = (const float*)d_in[0];
  const float* w1 = (const float*)d_in[1];
  const float* b1 = (const float*)d_in[2];
  const float* w2 = (const float*)d_in[3];
  const float* b2 = (const float*)d_in[4];
  float* out = (float*)d_out;

  // workspace layout
  const size_t w2t_elems = (size_t)NI * NC;          // 4,096,000 floats
  const size_t part_elems = (size_t)NB * NSPLIT;     // 131,072
  const size_t need_full = (w2t_elems + part_elems) * 4 + part_elems * 4;
  const bool have_w2t = ws_size >= need_full;

  float* w2t = (float*)d_ws;
  float* pval;
  int* pidx;
  if (have_w2t) {
    pval = (float*)d_ws + w2t_elems;
    pidx = (int*)((float*)d_ws + w2t_elems + part_elems);
  } else {
    pval = (float*)d_ws;
    pidx = (int*)((float*)d_ws + part_elems);
  }

  // 1) argmax GEMM
  dim3 ggrid(NB / BM, NSPLIT);
  argmax_gemm<<<ggrid, 256, 0, stream>>>(x, w1, b1, pval, pidx);

  if (have_w2t) {
    // 2) transpose w2 (independent of kernel 1)
    dim3 tgrid(NI / 32, (NC + 31) / 32);
    dim3 tblock(32, 8);
    transpose_w2<<<tgrid, tblock, 0, stream>>>(w2, w2t);
    // 3) merge + gather
    merge_gather<<<NB, 256, 0, stream>>>(pval, pidx, w2t, b2, out);
  } else {
    merge_gather_direct<<<NB, 256, 0, stream>>>(pval, pidx, w2, b2, out);
  }
}

// Round 4
// 1353.125 us; speedup vs baseline: 3.1468x; 3.1468x over previous
//
#include <hip/hip_runtime.h>
#include <hip/hip_bf16.h>
#include <math.h>

typedef unsigned short u16;
typedef unsigned int u32;
typedef __attribute__((ext_vector_type(8))) short short8;
typedef __attribute__((ext_vector_type(4))) float floatx4;

// Problem constants
constexpr int NB = 16384;   // batch rows
constexpr int NF = 2048;    // features (K)
constexpr int NI = 4096;    // intermediate (cols of h)
constexpr int NC = 1000;    // classes
constexpr int NBLK_N = NI / 128;          // 32 column blocks in MFMA path
constexpr int NSLOT = NBLK_N * 4;         // 4 entries per block: top-2 x 2 col-halves
constexpr float EPS_MARGIN = 1e-2f;       // candidate margin (approx err ~1e-4 worst)

// ---------------------------------------------------------------------------
// helpers
// ---------------------------------------------------------------------------
__device__ inline u16 f32_bf16_rne(float f) {
  u32 u = __float_as_uint(f);
  u32 r = (u + 0x7fffu + ((u >> 16) & 1u)) >> 16;
  return (u16)r;
}
__device__ inline float bf16_f32(u16 h) { return __uint_as_float(((u32)h) << 16); }

__device__ inline void async16(const u16* g, u16* l) {
  __builtin_amdgcn_global_load_lds((const __attribute__((address_space(1))) void*)g,
                                   (__attribute__((address_space(3))) void*)l,
                                   16, 0, 0);
}

// ---------------------------------------------------------------------------
// Split fp32 -> bf16 hi + bf16 residual. 4 elems/thread. Thread 0 of block 0
// zeroes the ambiguity counter (ws re-poisoned to 0xAA before every launch).
// ---------------------------------------------------------------------------
__global__ __launch_bounds__(256) void split_bf16(const float* __restrict__ in,
                                                  u16* __restrict__ hi,
                                                  u16* __restrict__ lo, int n4,
                                                  int* zero_me) {
  int i = blockIdx.x * 256 + threadIdx.x;
  if (i == 0 && zero_me) { zero_me[0] = 0; }
  if (i >= n4) return;
  float4 v = ((const float4*)in)[i];
  u16 h0 = f32_bf16_rne(v.x);
  u16 h1 = f32_bf16_rne(v.y);
  u16 h2 = f32_bf16_rne(v.z);
  u16 h3 = f32_bf16_rne(v.w);
  ushort4 hv;
  hv.x = h0; hv.y = h1; hv.z = h2; hv.w = h3;
  ushort4 lv;
  lv.x = f32_bf16_rne(v.x - bf16_f32(h0));
  lv.y = f32_bf16_rne(v.y - bf16_f32(h1));
  lv.z = f32_bf16_rne(v.z - bf16_f32(h2));
  lv.w = f32_bf16_rne(v.w - bf16_f32(h3));
  ((ushort4*)hi)[i] = hv;
  ((ushort4*)lo)[i] = lv;
}

// ---------------------------------------------------------------------------
// MFMA split-bf16 GEMM with fused per-row top-2 argmax. 128x128 tile, K-step
// 32, 4 waves; wave wv stages matrix wv via global_load_lds. Each wave owns a
// 64x64 quadrant; per-(row, col-half) top-2 written to DISJOINT slots
// (slot = bx*4 + (wcol>>5) + {0,1}).
// ---------------------------------------------------------------------------
__global__ __launch_bounds__(256) void mfma_split_argmax(
    const u16* __restrict__ xh, const u16* __restrict__ xl,
    const u16* __restrict__ wh, const u16* __restrict__ wl,
    const float* __restrict__ b1, float* __restrict__ pval,
    int* __restrict__ pidx) {
  __shared__ __attribute__((aligned(16))) u16 lds[4][128][32];
  const int t = threadIdx.x;
  const int wv = t >> 6;
  const int l = t & 63;
  const int n0 = blockIdx.x * 128;
  const int m0 = blockIdx.y * 128;
  const int wrow = (wv & 1) * 64;
  const int wcol = (wv >> 1) * 64;

  const u16* src;
  if (wv == 0) src = xh + (size_t)m0 * NF;
  else if (wv == 1) src = xl + (size_t)m0 * NF;
  else if (wv == 2) src = wh + (size_t)n0 * NF;
  else src = wl + (size_t)n0 * NF;
  const u16* lsrc = src + (size_t)(l >> 2) * NF + (l & 3) * 8;
  u16* ldsw = &lds[wv][0][0];

  floatx4 acc[4][4];
#pragma unroll
  for (int i = 0; i < 4; ++i)
#pragma unroll
    for (int j = 0; j < 4; ++j) acc[i][j] = (floatx4){0.f, 0.f, 0.f, 0.f};

  const int fr = l & 15;  // A-row / B-col within 16-tile; also C col
  const int q = l >> 4;   // quad: k-granule for A/B, row-group for C

  for (int kt = 0; kt < NF; kt += 32) {
#pragma unroll
    for (int inst = 0; inst < 8; ++inst) {
      async16(lsrc + kt + inst * 16 * NF, ldsw + inst * 16 * 32);
    }
    __syncthreads();
    short8 ah[4], al[4], bh[4], bl[4];
#pragma unroll
    for (int i = 0; i < 4; ++i) {
      ah[i] = *(const short8*)&lds[0][wrow + i * 16 + fr][q * 8];
      al[i] = *(const short8*)&lds[1][wrow + i * 16 + fr][q * 8];
      bh[i] = *(const short8*)&lds[2][wcol + i * 16 + fr][q * 8];
      bl[i] = *(const short8*)&lds[3][wcol + i * 16 + fr][q * 8];
    }
#pragma unroll
    for (int mt = 0; mt < 4; ++mt)
#pragma unroll
      for (int nt = 0; nt < 4; ++nt) {
        acc[mt][nt] = __builtin_amdgcn_mfma_f32_16x16x32_bf16(ah[mt], bh[nt], acc[mt][nt], 0, 0, 0);
        acc[mt][nt] = __builtin_amdgcn_mfma_f32_16x16x32_bf16(ah[mt], bl[nt], acc[mt][nt], 0, 0, 0);
        acc[mt][nt] = __builtin_amdgcn_mfma_f32_16x16x32_bf16(al[mt], bh[nt], acc[mt][nt], 0, 0, 0);
      }
    __syncthreads();
  }

  // Epilogue: bias + per-row top-2 over this wave's 64 cols.
  float bv[4];
#pragma unroll
  for (int nt = 0; nt < 4; ++nt) bv[nt] = b1[n0 + wcol + nt * 16 + fr];

#pragma unroll
  for (int mt = 0; mt < 4; ++mt) {
#pragma unroll
    for (int r = 0; r < 4; ++r) {
      float v1 = -INFINITY, v2 = -INFINITY;
      int i1 = 0x7fffffff, i2 = 0x7fffffff;
#pragma unroll
      for (int nt = 0; nt < 4; ++nt) {
        float v = acc[mt][nt][r] + bv[nt];
        int c = n0 + wcol + nt * 16 + fr;
        if (v > v1 || (v == v1 && c < i1)) {
          v2 = v1; i2 = i1; v1 = v; i1 = c;
        } else if (v > v2 || (v == v2 && c < i2)) {
          v2 = v; i2 = c;
        }
      }
      // reduce top-2 across the 16 lanes sharing this row (low 4 lane bits)
#pragma unroll
      for (int mm = 1; mm < 16; mm <<= 1) {
        float ov1 = __shfl_xor(v1, mm);
        int oi1 = __shfl_xor(i1, mm);
        float ov2 = __shfl_xor(v2, mm);
        int oi2 = __shfl_xor(i2, mm);
        if (ov1 > v1 || (ov1 == v1 && oi1 < i1)) {
          float nv2; int ni2;
          if (v1 > ov2 || (v1 == ov2 && i1 < oi2)) { nv2 = v1; ni2 = i1; }
          else { nv2 = ov2; ni2 = oi2; }
          v1 = ov1; i1 = oi1; v2 = nv2; i2 = ni2;
        } else if (ov1 > v2 || (ov1 == v2 && oi1 < i2)) {
          v2 = ov1; i2 = oi1;
        }
      }
      if (fr == 0) {
        int row = m0 + wrow + mt * 16 + q * 4 + r;
        size_t base = (size_t)row * NSLOT + blockIdx.x * 4 + (wcol >> 5);
        pval[base] = v1; pidx[base] = i1;
        pval[base + 1] = v2; pidx[base + 1] = i2;
      }
    }
  }
}

// ---------------------------------------------------------------------------
// Merge per-slot top-2 -> global approx argmax; flag ambiguous rows.
// ---------------------------------------------------------------------------
__global__ __launch_bounds__(256) void merge_rows(const float* __restrict__ pval,
                                                  const int* __restrict__ pidx,
                                                  int* __restrict__ idxfinal,
                                                  int* __restrict__ amb,
                                                  int* __restrict__ counter) {
  int row = blockIdx.x * 256 + threadIdx.x;
  if (row >= NB) return;
  const float* pv = pval + (size_t)row * NSLOT;
  const int* pi = pidx + (size_t)row * NSLOT;
  float best = -INFINITY;
  int bi = 0x7fffffff;
  for (int e = 0; e < NSLOT; ++e) {
    float v = pv[e];
    int ix = pi[e];
    if (v > best || (v == best && ix < bi)) { best = v; bi = ix; }
  }
  idxfinal[row] = bi;
  float thr = best - EPS_MARGIN;
  int cnt = 0;
  for (int e = 0; e < NSLOT; ++e) cnt += (pv[e] >= thr) ? 1 : 0;
  if (cnt > 1) {
    int p = atomicAdd(counter, 1);
    if (p < NB) amb[p] = row;
  }
}

// ---------------------------------------------------------------------------
// Resolve: for each flagged row, recompute candidate columns with the EXACT
// arithmetic of the known-passing R1 fp32 kernel: a sequential ascending-k
// fmaf chain (acc = fma(x[k], w1[col][k], acc)), then one + b1[col] add.
// One wave per row; lane L handles slots L and L+64. Wave-argmax with
// tie -> smaller column reproduces numpy first-max semantics.
// ---------------------------------------------------------------------------
__global__ __launch_bounds__(256) void resolve_chain(
    const float* __restrict__ x, const float* __restrict__ w1,
    const float* __restrict__ b1, const float* __restrict__ pval,
    const int* __restrict__ pidx, const int* __restrict__ amb,
    const int* __restrict__ counter, int* __restrict__ idxfinal) {
  const int wave = threadIdx.x >> 6;
  const int lane = threadIdx.x & 63;
  int total = counter[0];
  if (total > NB) total = NB;
  for (int e = blockIdx.x * 4 + wave; e < total; e += gridDim.x * 4) {
    const int row = amb[e];
    const float* pv = pval + (size_t)row * NSLOT;
    const int* pi = pidx + (size_t)row * NSLOT;
    // wave-wide max of slot values -> threshold
    float m0 = pv[lane];
    float m1 = pv[lane + 64];
    float mv = fmaxf(m0, m1);
#pragma unroll
    for (int mm = 1; mm < 64; mm <<= 1) mv = fmaxf(mv, __shfl_xor(mv, mm));
    const float thr = mv - EPS_MARGIN;

    float bestv = -INFINITY;
    int besti = 0x7fffffff;
    const float* xr = x + (size_t)row * NF;
#pragma unroll
    for (int half = 0; half < 2; ++half) {
      const float v = half ? m1 : m0;
      if (v >= thr) {
        const int col = pi[lane + half * 64];
        const float* wr = w1 + (size_t)col * NF;
        float acc = 0.0f;
#pragma unroll 8
        for (int k = 0; k < NF; ++k) acc = fmaf(xr[k], wr[k], acc);
        const float val = acc + b1[col];
        if (val > bestv || (val == bestv && col < besti)) { bestv = val; besti = col; }
      }
    }
    // wave argmax, tie -> smaller column
#pragma unroll
    for (int mm = 1; mm < 64; mm <<= 1) {
      float ov = __shfl_xor(bestv, mm);
      int oi = __shfl_xor(besti, mm);
      if (ov > bestv || (ov == bestv && oi < besti)) { bestv = ov; besti = oi; }
    }
    if (lane == 0 && besti != 0x7fffffff) idxfinal[row] = besti;
  }
}

// ---------------------------------------------------------------------------
// w2 transpose + final gather (coalesced path), plus direct-gather fallback
// ---------------------------------------------------------------------------
__global__ __launch_bounds__(256) void transpose_w2(const float* __restrict__ w2,
                                                    float* __restrict__ w2t) {
  __shared__ float tile[32][33];
  const int x = blockIdx.x * 32 + threadIdx.x;  // col in w2 (0..NI)
  const int y0 = blockIdx.y * 32;               // row in w2 (0..NC)
  for (int j = threadIdx.y; j < 32; j += 8) {
    const int y = y0 + j;
    tile[j][threadIdx.x] = (y < NC) ? w2[(size_t)y * NI + x] : 0.0f;
  }
  __syncthreads();
  const int xo = y0 + threadIdx.x;
  const int yo0 = blockIdx.x * 32;
  for (int j = threadIdx.y; j < 32; j += 8) {
    const int yo = yo0 + j;
    if (xo < NC) w2t[(size_t)yo * NC + xo] = tile[threadIdx.x][j];
  }
}

__global__ __launch_bounds__(256) void gather_out(const int* __restrict__ idxfinal,
                                                  const float* __restrict__ w2t,
                                                  const float* __restrict__ b2,
                                                  float* __restrict__ out) {
  const int b = blockIdx.x;
  const int ix = idxfinal[b];
  const float4* src = (const float4*)(w2t + (size_t)ix * NC);
  const float4* bb = (const float4*)b2;
  float4* dst = (float4*)(out + (size_t)b * NC);
  const int t = threadIdx.x;
  if (t < NC / 4) {
    float4 v = src[t];
    float4 w = bb[t];
    float4 o;
    o.x = v.x + w.x; o.y = v.y + w.y; o.z = v.z + w.z; o.w = v.w + w.w;
    dst[t] = o;
  }
}

__global__ __launch_bounds__(256) void gather_out_direct(
    const int* __restrict__ idxfinal, const float* __restrict__ w2,
    const float* __restrict__ b2, float* __restrict__ out) {
  const int b = blockIdx.x;
  const int ix = idxfinal[b];
  for (int c = threadIdx.x; c < NC; c += 256) {
    out[(size_t)b * NC + c] = w2[(size_t)c * NI + ix] + b2[c];
  }
}

// ===========================================================================
// Fallback fp32 path (round-1, known-passing) if workspace is too small.
// ===========================================================================
constexpr int BM = 64, BN = 64, BK = 32, TM = 4, TN = 4;
constexpr int NSPLIT = 8;
constexpr int COLS_PER_SPLIT = NI / NSPLIT;
constexpr int NCHUNK = COLS_PER_SPLIT / BN;
constexpr int LDS_STRIDE = BM + 4;

__global__ __launch_bounds__(256) void argmax_gemm(
    const float* __restrict__ x, const float* __restrict__ w1,
    const float* __restrict__ b1, float* __restrict__ pval,
    int* __restrict__ pidx) {
  __shared__ float xs[BK][LDS_STRIDE];
  __shared__ float ws[BK][LDS_STRIDE];
  const int t = threadIdx.x;
  const int tx = t & 15;
  const int ty = t >> 4;
  const int m0 = blockIdx.x * BM;
  const int split = blockIdx.y;
  const int n0 = split * COLS_PER_SPLIT;
  const int lrow = t >> 3;
  const int lk4 = (t & 7) << 2;
  float rmax[TM];
  int ridx[TM];
#pragma unroll
  for (int i = 0; i < TM; ++i) { rmax[i] = -INFINITY; ridx[i] = 0; }
  for (int chunk = 0; chunk < NCHUNK; ++chunk) {
    const int nb = n0 + chunk * BN;
    float acc[TM][TN];
#pragma unroll
    for (int i = 0; i < TM; ++i)
#pragma unroll
      for (int j = 0; j < TN; ++j) acc[i][j] = 0.0f;
    for (int kt = 0; kt < NF; kt += BK) {
      __syncthreads();
#pragma unroll
      for (int p = 0; p < 2; ++p) {
        const int row = p * 32 + lrow;
        const float4 v = *(const float4*)(x + (size_t)(m0 + row) * NF + kt + lk4);
        xs[lk4 + 0][row] = v.x; xs[lk4 + 1][row] = v.y;
        xs[lk4 + 2][row] = v.z; xs[lk4 + 3][row] = v.w;
        const float4 u = *(const float4*)(w1 + (size_t)(nb + row) * NF + kt + lk4);
        ws[lk4 + 0][row] = u.x; ws[lk4 + 1][row] = u.y;
        ws[lk4 + 2][row] = u.z; ws[lk4 + 3][row] = u.w;
      }
      __syncthreads();
#pragma unroll
      for (int k = 0; k < BK; ++k) {
        const float4 av = *(const float4*)&xs[k][ty * TM];
        const float4 bv = *(const float4*)&ws[k][tx * TN];
        const float a[TM] = {av.x, av.y, av.z, av.w};
        const float b[TN] = {bv.x, bv.y, bv.z, bv.w};
#pragma unroll
        for (int i = 0; i < TM; ++i)
#pragma unroll
          for (int j = 0; j < TN; ++j) acc[i][j] = fmaf(a[i], b[j], acc[i][j]);
      }
    }
#pragma unroll
    for (int j = 0; j < TN; ++j) {
      const int col = nb + tx * TN + j;
      const float bj = b1[col];
#pragma unroll
      for (int i = 0; i < TM; ++i) {
        const float v = acc[i][j] + bj;
        if (v > rmax[i]) { rmax[i] = v; ridx[i] = col; }
      }
    }
  }
#pragma unroll
  for (int m = 1; m < 16; m <<= 1) {
#pragma unroll
    for (int i = 0; i < TM; ++i) {
      const float v2 = __shfl_xor(rmax[i], m);
      const int i2 = __shfl_xor(ridx[i], m);
      if (v2 > rmax[i] || (v2 == rmax[i] && i2 < ridx[i])) { rmax[i] = v2; ridx[i] = i2; }
    }
  }
  if (tx == 0) {
#pragma unroll
    for (int i = 0; i < TM; ++i) {
      const int row = m0 + ty * TM + i;
      pval[(size_t)row * NSPLIT + split] = rmax[i];
      pidx[(size_t)row * NSPLIT + split] = ridx[i];
    }
  }
}

__global__ __launch_bounds__(256) void merge_gather_direct(
    const float* __restrict__ pval, const int* __restrict__ pidx,
    const float* __restrict__ w2, const float* __restrict__ b2,
    float* __restrict__ out) {
  const int b = blockIdx.x;
  __shared__ int sidx;
  if (threadIdx.x == 0) {
    float best = -INFINITY;
    int bi = 0;
    for (int s = 0; s < NSPLIT; ++s) {
      const float v = pval[(size_t)b * NSPLIT + s];
      const int ix = pidx[(size_t)b * NSPLIT + s];
      if (v > best || (v == best && ix < bi)) { best = v; bi = ix; }
    }
    sidx = bi;
  }
  __syncthreads();
  const int ix = sidx;
  for (int c = threadIdx.x; c < NC; c += 256) {
    out[(size_t)b * NC + c] = w2[(size_t)c * NI + ix] + b2[c];
  }
}

// ===========================================================================
extern "C" void kernel_launch(void* const* d_in, const int* in_sizes, int n_in,
                              void* d_out, int out_size, void* d_ws, size_t ws_size,
                              hipStream_t stream) {
  const float* x = (const float*)d_in[0];
  const float* w1 = (const float*)d_in[1];
  const float* b1 = (const float*)d_in[2];
  const float* w2 = (const float*)d_in[3];
  const float* b2 = (const float*)d_in[4];
  float* out = (float*)d_out;

  // workspace layout (bytes)
  const size_t sz_xh = (size_t)NB * NF * 2;          // 67108864
  const size_t sz_wh = (size_t)NI * NF * 2;          // 16777216
  const size_t sz_pv = (size_t)NB * NSLOT * 4;       // 8388608
  const size_t sz_idx = (size_t)NB * 4;              // 65536
  const size_t sz_w2t = (size_t)NI * NC * 4;         // 16384000
  const size_t NEED_CORE = 2 * sz_xh + 2 * sz_wh + 2 * sz_pv + 2 * sz_idx + 16;
  const size_t NEED_FULL = NEED_CORE + sz_w2t;

  if (ws_size >= NEED_CORE) {
    char* p = (char*)d_ws;
    u16* xh = (u16*)p; p += sz_xh;
    u16* xl = (u16*)p; p += sz_xh;
    u16* wh = (u16*)p; p += sz_wh;
    u16* wl = (u16*)p; p += sz_wh;
    float* pval = (float*)p; p += sz_pv;
    int* pidx = (int*)p; p += sz_pv;
    int* idxfinal = (int*)p; p += sz_idx;
    int* amb = (int*)p; p += sz_idx;
    int* counter = (int*)p; p += 16;
    const bool have_w2t = ws_size >= NEED_FULL;
    float* w2t = (float*)p;

    split_bf16<<<(NB * NF / 4 + 255) / 256, 256, 0, stream>>>(x, xh, xl, NB * NF / 4, counter);
    split_bf16<<<(NI * NF / 4 + 255) / 256, 256, 0, stream>>>(w1, wh, wl, NI * NF / 4, nullptr);
    if (have_w2t) {
      dim3 tgrid(NI / 32, (NC + 31) / 32);
      dim3 tblock(32, 8);
      transpose_w2<<<tgrid, tblock, 0, stream>>>(w2, w2t);
    }

    dim3 ggrid(NI / 128, NB / 128);  // n fast-varying for x-tile L2 reuse
    mfma_split_argmax<<<ggrid, 256, 0, stream>>>(xh, xl, wh, wl, b1, pval, pidx);

    merge_rows<<<NB / 256, 256, 0, stream>>>(pval, pidx, idxfinal, amb, counter);
    resolve_chain<<<256, 256, 0, stream>>>(x, w1, b1, pval, pidx, amb, counter, idxfinal);
    if (have_w2t) {
      gather_out<<<NB, 256, 0, stream>>>(idxfinal, w2t, b2, out);
    } else {
      gather_out_direct<<<NB, 256, 0, stream>>>(idxfinal, w2, b2, out);
    }
  } else {
    // fp32 fallback (round-1 path)
    float* pval = (float*)d_ws;
    int* pidx = (int*)((float*)d_ws + (size_t)NB * NSPLIT);
    dim3 ggrid(NB / BM, NSPLIT);
    argmax_gemm<<<ggrid, 256, 0, stream>>>(x, w1, b1, pval, pidx);
    merge_gather_direct<<<NB, 256, 0, stream>>>(pval, pidx, w2, b2, out);
  }
}